// Round 11
// baseline (86.674 us; speedup 1.0000x reference)
//
#include <hip/hip_runtime.h>

// MMD loss, MI355X. Round 10: wave-persistent slab GEMM. 128 slabs of 64 rows;
// each wave owns 4 triangle slab-pairs, holds its A-slab (64x512 int8 = 128
// VGPR) across a streaming B ping-pong pipeline. No barriers, no atomics,
// no memset. int8 exact-quantized-MMD framing as rounds 5-9.
//
// ws layout (ws is ~268 MB; we use < 6 MB):
//   [0,32768)          float sq[8192]      sum q^2 per row (integer-exact)
//   [32768,557056)     float vp[256][512]  per-block col sums of q
//   [557056,557060)    float craw
//   [557184,565440)    float Fpart[2064]   one partial per wave
//   [1048576,+4 MiB)   int8 img: 64 panels x 8 kp x 8 groups x 64 lanes x 16B
//     lane chunk = rows g*16+(lane&15), cols kp*64 + (lane>>4)*16 .. +16

typedef int i32x4 __attribute__((ext_vector_type(4)));

#define N_TOT  8192
#define DIM    512
#define QSCALE 24.0f
#define NSLAB  128
#define NWAVE  2064      // 8256 pairs / 4 per wave
#define NBLK   516       // NWAVE / 4 waves per block
#define SQ_OFF   0
#define VP_OFF   32768
#define CRAW_OFF 557056
#define FP_OFF   557184
#define IMG_OFF  1048576ULL

__device__ __forceinline__ int q8(float x) {
    int q = __float2int_rn(x * QSCALE);
    return max(-127, min(127, q));
}

// pre-pass: 256 blocks = (panel p, quarter q4: 32 rows). Full row-sq per
// block (no atomics); col sums into vp[block][512]; fragment-major i8 image.
__global__ __launch_bounds__(256) void k_pre(
    const float* __restrict__ src, const float* __restrict__ tgt,
    unsigned char* __restrict__ img,
    float* __restrict__ sq, float* __restrict__ vp)
{
    __shared__ __align__(16) signed char qt[32][528];
    const int b = blockIdx.x;
    const int p = b >> 2, q4 = b & 3;
    const int t = threadIdx.x;
    const float* base = ((p < 32) ? src + (size_t)p * 128 * DIM
                                  : tgt + (size_t)(p - 32) * 128 * DIM)
                        + (size_t)(q4 * 32) * DIM;
    {
        int r = t >> 3, seg = t & 7;           // 8 threads/row, 64 cols each
        const float* qp = base + (size_t)r * DIM + seg * 64;
        float rsq = 0.f;
        #pragma unroll
        for (int j = 0; j < 16; ++j) {
            float4 x = *(const float4*)(qp + j * 4);
            int q0 = q8(x.x), q1 = q8(x.y), q2 = q8(x.z), q3 = q8(x.w);
            unsigned int w = (q0 & 255) | ((q1 & 255) << 8) | ((q2 & 255) << 16)
                             | ((unsigned)(q3 & 255) << 24);
            *(unsigned int*)&qt[r][seg * 64 + j * 4] = w;
            rsq += (float)(q0 * q0 + q1 * q1 + q2 * q2 + q3 * q3);
        }
        rsq += __shfl_xor(rsq, 1);
        rsq += __shfl_xor(rsq, 2);
        rsq += __shfl_xor(rsq, 4);
        if (seg == 0) sq[p * 128 + q4 * 32 + r] = rsq;
    }
    __syncthreads();
    // fragment emit: 1024 chunks = kp(8) x g_l(2) x lane(64); 4 per thread
    #pragma unroll
    for (int h = 0; h < 4; ++h) {
        int c = t + h * 256;
        int kp = c >> 7, g_l = (c >> 6) & 1, lane = c & 63;
        int row = g_l * 16 + (lane & 15), col = kp * 64 + (lane >> 4) * 16;
        uint4 w = *(const uint4*)&qt[row][col];
        *(uint4*)(img + (size_t)p * 65536 + (size_t)kp * 8192
                  + (size_t)(q4 * 2 + g_l) * 1024 + (size_t)lane * 16) = w;
    }
    // col sums (32 rows) -> vp[b]
    {
        float s0 = 0.f, s1 = 0.f;
        #pragma unroll 8
        for (int r = 0; r < 32; ++r) {
            s0 += (float)qt[r][t];
            s1 += (float)qt[r][t + 256];
        }
        vp[(size_t)b * 512 + t]       = s0;
        vp[(size_t)b * 512 + t + 256] = s1;
    }
}

// craw = log2e / (16 * bw_raw); bw_raw = (2n*S - 2||v||^2)/(n^2-n)/4
__global__ void k3_bw(const float* __restrict__ sq, const float* __restrict__ vp,
                      float* __restrict__ craw) {
    int t = threadIdx.x;   // 512 threads
    double s = 0.0;
    for (int i = t; i < N_TOT; i += 512) s += (double)sq[i];
    float vs = 0.f;
    for (int b = 0; b < 256; ++b) vs += vp[(size_t)b * 512 + t];
    double vv = (double)vs * vs;
    #pragma unroll
    for (int off = 32; off > 0; off >>= 1) {
        s  += __shfl_down(s, off);
        vv += __shfl_down(vv, off);
    }
    __shared__ double rs[8], rv[8];
    if ((t & 63) == 0) { rs[t >> 6] = s; rv[t >> 6] = vv; }
    __syncthreads();
    if (t == 0) {
        double S = 0.0, V = 0.0;
        for (int i = 0; i < 8; ++i) { S += rs[i]; V += rv[i]; }
        double sumd2 = 2.0 * (double)N_TOT * S - 2.0 * V;
        double bw = sumd2 / ((double)N_TOT * N_TOT - (double)N_TOT) / 4.0;
        *craw = (float)(1.4426950408889634 / (16.0 * bw));
    }
}

#define LB(BUF, KP)                                                   \
    do {                                                              \
        BUF[0] = *(const i32x4*)(pB + (KP) * 8192 + lofs);            \
        BUF[1] = *(const i32x4*)(pB + (KP) * 8192 + 1024 + lofs);     \
        BUF[2] = *(const i32x4*)(pB + (KP) * 8192 + 2048 + lofs);     \
        BUF[3] = *(const i32x4*)(pB + (KP) * 8192 + 3072 + lofs);     \
    } while (0)

#define MF4(KP, BUF)                                                           \
    do {                                                                       \
        _Pragma("unroll")                                                      \
        for (int m_ = 0; m_ < 4; ++m_)                                         \
            _Pragma("unroll")                                                  \
            for (int n_ = 0; n_ < 4; ++n_)                                     \
                acc[m_][n_] = __builtin_amdgcn_mfma_i32_16x16x64_i8(           \
                    A_[(KP) * 4 + m_], BUF[n_], acc[m_][n_], 0, 0, 0);         \
    } while (0)

__global__ __launch_bounds__(256, 2) void kmain(
    const unsigned char* __restrict__ img,
    const float* __restrict__ sq, const float* __restrict__ craw_p,
    float* __restrict__ Fpart)
{
    const int tid  = threadIdx.x;
    const int lane = tid & 63;
    const int wid  = tid >> 6;
    const int wgid = blockIdx.x * 4 + wid;
    const int lhi  = lane >> 4, llo = lane & 15;
    const int lofs = lane * 16;
    const char* ic = (const char*)img;

    // wave -> first pair (si, sj): 4 consecutive pairs in row-major triangle
    int q = wgid * 4;
    int si = 0;
    while (q >= NSLAB - si) { q -= NSLAB - si; ++si; }
    int sj = si + q;

    const float c = *craw_p;

    i32x4 A_[32];              // 64x512 int8 A-slab, all K
    float local = 0.f;
    bool needA = true;

    #pragma unroll 1
    for (int e = 0; e < 4; ++e) {
        if (needA) {
            const char* pA = ic + (size_t)(si >> 1) * 65536 + (size_t)(si & 1) * 4096;
            #pragma unroll
            for (int kp = 0; kp < 8; ++kp)
                #pragma unroll
                for (int m = 0; m < 4; ++m)
                    A_[kp * 4 + m] = *(const i32x4*)(pA + kp * 8192 + m * 1024 + lofs);
            needA = false;
        }
        const char* pB = ic + (size_t)(sj >> 1) * 65536 + (size_t)(sj & 1) * 4096;

        i32x4 acc[4][4];
        #pragma unroll
        for (int m = 0; m < 4; ++m)
            #pragma unroll
            for (int n = 0; n < 4; ++n) acc[m][n] = (i32x4){0, 0, 0, 0};

        i32x4 B0[4], B1[4];
        LB(B0, 0);
        LB(B1, 1); MF4(0, B0);
        LB(B0, 2); MF4(1, B1);
        LB(B1, 3); MF4(2, B0);
        LB(B0, 4); MF4(3, B1);
        LB(B1, 5); MF4(4, B0);
        LB(B0, 6); MF4(5, B1);
        LB(B1, 7); MF4(6, B0);
        MF4(7, B1);

        // epilogue for this pair
        float sgn  = ((si < 64) == (sj < 64)) ? 1.f : -1.f;
        const bool diag = (si == sj);
        float wpair = diag ? sgn : 2.f * sgn;
        float sqc_[4];
        #pragma unroll
        for (int n = 0; n < 4; ++n)
            sqc_[n] = sq[sj * 64 + n * 16 + llo];
        float psum = 0.f;
        #pragma unroll
        for (int m = 0; m < 4; ++m) {
            float sqr_[4];
            #pragma unroll
            for (int r = 0; r < 4; ++r)
                sqr_[r] = sq[si * 64 + m * 16 + lhi * 4 + r];
            #pragma unroll
            for (int n = 0; n < 4; ++n)
                #pragma unroll
                for (int r = 0; r < 4; ++r) {
                    float d2 = sqr_[r] + sqc_[n] - 2.f * (float)acc[m][n][r];
                    d2 = fmaxf(d2, 0.f);
                    float u = __builtin_amdgcn_exp2f(-d2 * c);
                    float u2 = u * u, u4 = u2 * u2, u8 = u4 * u4, u16 = u8 * u8;
                    float k5 = u + u2 + u4 + u8 + u16;
                    if (diag) {
                        int ri = m * 16 + lhi * 4 + r;
                        int cj = n * 16 + llo;
                        k5 *= (cj > ri) ? 2.f : ((cj == ri) ? 1.f : 0.f);
                    }
                    psum += k5;
                }
        }
        local += wpair * psum;

        ++sj;
        if (sj == NSLAB) { ++si; sj = si; needA = true; }
    }

    #pragma unroll
    for (int off = 32; off > 0; off >>= 1) local += __shfl_down(local, off);
    if (lane == 0) Fpart[wgid] = local;
}

__global__ void k4_out(const float* __restrict__ Fpart, float* __restrict__ out) {
    int t = threadIdx.x;
    double s = 0.0;
    for (int i = t; i < NWAVE; i += 256) s += (double)Fpart[i];
    #pragma unroll
    for (int off = 32; off > 0; off >>= 1) s += __shfl_down(s, off);
    __shared__ double r[4];
    if ((t & 63) == 0) r[t >> 6] = s;
    __syncthreads();
    if (t == 0) out[0] = (float)((r[0] + r[1] + r[2] + r[3]) / ((double)4096 * 4096.0));
}

extern "C" void kernel_launch(void* const* d_in, const int* in_sizes, int n_in,
                              void* d_out, int out_size, void* d_ws, size_t ws_size,
                              hipStream_t stream) {
    const float* src = (const float*)d_in[0];
    const float* tgt = (const float*)d_in[1];
    char* ws = (char*)d_ws;
    float* sq    = (float*)(ws + SQ_OFF);
    float* vp    = (float*)(ws + VP_OFF);
    float* craw  = (float*)(ws + CRAW_OFF);
    float* Fpart = (float*)(ws + FP_OFF);
    unsigned char* img = (unsigned char*)(ws + IMG_OFF);
    float* out = (float*)d_out;

    hipLaunchKernelGGL(k_pre, dim3(256), dim3(256), 0, stream, src, tgt, img, sq, vp);
    hipLaunchKernelGGL(k3_bw, dim3(1), dim3(512), 0, stream, sq, vp, craw);
    hipLaunchKernelGGL(kmain, dim3(NBLK), dim3(256), 0, stream, img, sq, craw, Fpart);
    hipLaunchKernelGGL(k4_out, dim3(1), dim3(256), 0, stream, Fpart, out);
}

// Round 12
// 60.090 us; speedup vs baseline: 1.4424x; 1.4424x over previous
//
#include <hip/hip_runtime.h>

// MMD loss, MI355X. Round 11: A-slab staged once per block into LDS (no
// in-loop barriers), B streamed from global with SGPR addressing, 8 pairs
// per block (2 per wave), craw fused at block start. int8 exact-quantized
// MMD framing as rounds 5-10.
//
// ws layout:
//   [0,32768)        float sq[8192]     sum q^2 per row (integer-exact)
//   [32768,34816)    float v[512]       col sums of q (integer-exact)
//   [295040,312448)  float Fpart[4352]  one per wave
//   [327680,+4 MiB)  int8 img: 64 panels x 8 kp x 8 groups x 64 lanes x 16B
//     lane chunk = rows g*16+(lane&15), cols kp*64 + (lane>>4)*16 .. +16

typedef int i32x4 __attribute__((ext_vector_type(4)));

#define N_TOT  8192
#define DIM    512
#define QSCALE 24.0f
#define NSLAB  128
#define NBLK   1088      // sum_{si} ceil((128-si)/8) = 8*136
#define NWAVE  4352
#define FP_OFF 295040
#define IMG_OFF 327680ULL

__device__ __forceinline__ int q8(float x) {
    int q = __float2int_rn(x * QSCALE);
    return max(-127, min(127, q));
}

__device__ __forceinline__ void gload16(const void* g, void* l) {
    __builtin_amdgcn_global_load_lds(
        (const __attribute__((address_space(1))) unsigned int*)g,
        (__attribute__((address_space(3))) unsigned int*)l, 16, 0, 0);
}

// pre-pass: 512 blocks = (panel p, kp). 128 rows x 64 cols each. (R9 verified)
__global__ __launch_bounds__(256) void k_pre(
    const float* __restrict__ src, const float* __restrict__ tgt,
    unsigned char* __restrict__ img,
    float* __restrict__ sq, float* __restrict__ v)
{
    __shared__ __align__(16) signed char qt[128][80];
    const int b = blockIdx.x;
    const int p = b >> 3, kp = b & 7;
    const int t = threadIdx.x;
    const float* base = ((p < 32) ? src + (size_t)p * 128 * DIM
                                  : tgt + (size_t)(p - 32) * 128 * DIM) + kp * 64;
    {
        int r = t >> 1, ch = (t & 1) * 32;
        const float* qp = base + (size_t)r * DIM + ch;
        float rsq = 0.f;
        #pragma unroll
        for (int j = 0; j < 8; ++j) {
            float4 x = *(const float4*)(qp + j * 4);
            int q0 = q8(x.x), q1 = q8(x.y), q2 = q8(x.z), q3 = q8(x.w);
            unsigned int w = (q0 & 255) | ((q1 & 255) << 8) | ((q2 & 255) << 16)
                             | ((unsigned)(q3 & 255) << 24);
            *(unsigned int*)&qt[r][ch + j * 4] = w;
            rsq += (float)(q0 * q0 + q1 * q1 + q2 * q2 + q3 * q3);
        }
        rsq += __shfl_xor(rsq, 1);
        if ((t & 1) == 0) atomicAdd(&sq[p * 128 + r], rsq);
    }
    __syncthreads();
    #pragma unroll
    for (int h = 0; h < 2; ++h) {
        int ci = t + h * 256;                 // 0..511 = g*64 + lane
        int g = ci >> 6, lane = ci & 63;
        int row = g * 16 + (lane & 15), c0 = (lane >> 4) * 16;
        uint4 w = *(const uint4*)&qt[row][c0];
        *(uint4*)(img + (size_t)p * 65536 + (size_t)kp * 8192
                  + (size_t)g * 1024 + (size_t)lane * 16) = w;
    }
    if (t < 64) {
        float s = 0.f;
        for (int r = 0; r < 128; ++r) s += (float)qt[r][t];
        atomicAdd(&v[kp * 64 + t], s);
    }
}

// A fragments from LDS (all-immediate offsets; one addr VGPR)
#define LA(BUF, KP)                                                  \
    do {                                                             \
        BUF[0] = *(const i32x4*)(lA + (KP) * 4096 + lofs);           \
        BUF[1] = *(const i32x4*)(lA + (KP) * 4096 + 1024 + lofs);    \
        BUF[2] = *(const i32x4*)(lA + (KP) * 4096 + 2048 + lofs);    \
        BUF[3] = *(const i32x4*)(lA + (KP) * 4096 + 3072 + lofs);    \
    } while (0)

// B fragments from global (SGPR base via readfirstlane)
#define LB(BUF, KP)                                                  \
    do {                                                             \
        BUF[0] = *(const i32x4*)(pB + (KP) * 8192 + lofs);           \
        BUF[1] = *(const i32x4*)(pB + (KP) * 8192 + 1024 + lofs);    \
        BUF[2] = *(const i32x4*)(pB + (KP) * 8192 + 2048 + lofs);    \
        BUF[3] = *(const i32x4*)(pB + (KP) * 8192 + 3072 + lofs);    \
    } while (0)

#define MF(A, B)                                                               \
    do {                                                                       \
        _Pragma("unroll")                                                      \
        for (int m_ = 0; m_ < 4; ++m_)                                         \
            _Pragma("unroll")                                                  \
            for (int n_ = 0; n_ < 4; ++n_)                                     \
                acc[m_][n_] = __builtin_amdgcn_mfma_i32_16x16x64_i8(           \
                    A[m_], B[n_], acc[m_][n_], 0, 0, 0);                       \
    } while (0)

__global__ __launch_bounds__(256, 3) void kmain(
    const unsigned char* __restrict__ img,
    const float* __restrict__ sq, const float* __restrict__ v,
    float* __restrict__ Fpart)
{
    __shared__ __align__(16) char lA[32768];
    __shared__ float redS[4], redV[4];

    // XCD swizzle (1088 = 8*136), then (si, group-of-8-sj) walk
    int b = blockIdx.x;
    int s = (b & 7) * (NBLK / 8) + (b >> 3);
    int si = 0;
    while (s >= ((NSLAB - si + 7) >> 3)) { s -= (NSLAB - si + 7) >> 3; ++si; }
    // s is now the sj-group index g

    const int tid  = threadIdx.x;
    const int lane = tid & 63;
    const int wid  = tid >> 6;
    const int lhi  = lane >> 4, llo = lane & 15;
    const int lofs = lane * 16;
    const char* ic = (const char*)img;
    const char* gA = ic + (size_t)(si >> 1) * 65536 + (size_t)(si & 1) * 4096;

    // stage A-slab (64 rows x 512 cols int8 = 32 KB), once
    #pragma unroll
    for (int kp = 0; kp < 8; ++kp)
        gload16(gA + kp * 8192 + tid * 16, lA + kp * 4096 + wid * 1024);

    // craw partials overlap the staging DMA
    float Sp = 0.f;
    #pragma unroll
    for (int i = 0; i < 32; ++i) Sp += sq[tid + i * 256];
    float Vp;
    { float v0 = v[tid], v1 = v[tid + 256]; Vp = v0 * v0 + v1 * v1; }
    #pragma unroll
    for (int off = 32; off > 0; off >>= 1) {
        Sp += __shfl_down(Sp, off);
        Vp += __shfl_down(Vp, off);
    }
    if (lane == 0) { redS[wid] = Sp; redV[wid] = Vp; }
    __syncthreads();    // drains staging + publishes red
    float S = redS[0] + redS[1] + redS[2] + redS[3];
    float V = redV[0] + redV[1] + redV[2] + redV[3];
    float sumd2 = 2.f * (float)N_TOT * S - 2.f * V;
    float bw = sumd2 / ((float)N_TOT * (float)N_TOT - (float)N_TOT) * 0.25f;
    const float c = 1.4426950408889634f / (16.f * bw);

    float local = 0.f;
    const int sj_first = si + s * 8 + wid * 2;

    #pragma unroll
    for (int pp = 0; pp < 2; ++pp) {
        const int sj = sj_first + pp;
        if (sj < NSLAB) {
            const int sjs = __builtin_amdgcn_readfirstlane(sj);
            const char* pB = ic + (size_t)(sjs >> 1) * 65536 + (size_t)(sjs & 1) * 4096;

            i32x4 acc[4][4];
            #pragma unroll
            for (int m = 0; m < 4; ++m)
                #pragma unroll
                for (int n = 0; n < 4; ++n) acc[m][n] = (i32x4){0, 0, 0, 0};

            i32x4 A0[4], A1[4], B0[4], B1[4];
            LA(A0, 0); LB(B0, 0);
            LA(A1, 1); LB(B1, 1); MF(A0, B0);
            LA(A0, 2); LB(B0, 2); MF(A1, B1);
            LA(A1, 3); LB(B1, 3); MF(A0, B0);
            LA(A0, 4); LB(B0, 4); MF(A1, B1);
            LA(A1, 5); LB(B1, 5); MF(A0, B0);
            LA(A0, 6); LB(B0, 6); MF(A1, B1);
            LA(A1, 7); LB(B1, 7); MF(A0, B0);
            MF(A1, B1);

            const float sgn  = ((si < 64) == (sj < 64)) ? 1.f : -1.f;
            const bool  diag = (si == sj);
            const float wpair = diag ? sgn : 2.f * sgn;
            float sqc_[4];
            #pragma unroll
            for (int n = 0; n < 4; ++n)
                sqc_[n] = sq[sjs * 64 + n * 16 + llo];
            float psum = 0.f;
            #pragma unroll
            for (int m = 0; m < 4; ++m) {
                float sqr_[4];
                #pragma unroll
                for (int r = 0; r < 4; ++r)
                    sqr_[r] = sq[si * 64 + m * 16 + lhi * 4 + r];
                #pragma unroll
                for (int n = 0; n < 4; ++n)
                    #pragma unroll
                    for (int r = 0; r < 4; ++r) {
                        float d2 = sqr_[r] + sqc_[n] - 2.f * (float)acc[m][n][r];
                        d2 = fmaxf(d2, 0.f);
                        float u = __builtin_amdgcn_exp2f(-d2 * c);
                        float u2 = u * u, u4 = u2 * u2, u8 = u4 * u4, u16 = u8 * u8;
                        float k5 = u + u2 + u4 + u8 + u16;
                        if (diag) {
                            int ri = m * 16 + lhi * 4 + r;
                            int cj = n * 16 + llo;
                            k5 *= (cj > ri) ? 2.f : ((cj == ri) ? 1.f : 0.f);
                        }
                        psum += k5;
                    }
            }
            local += wpair * psum;
        }
    }

    #pragma unroll
    for (int off = 32; off > 0; off >>= 1) local += __shfl_down(local, off);
    if (lane == 0) Fpart[blockIdx.x * 4 + wid] = local;
}

__global__ void k4_out(const float* __restrict__ Fpart, float* __restrict__ out) {
    int t = threadIdx.x;
    double s = 0.0;
    for (int i = t; i < NWAVE; i += 256) s += (double)Fpart[i];
    #pragma unroll
    for (int off = 32; off > 0; off >>= 1) s += __shfl_down(s, off);
    __shared__ double r[4];
    if ((t & 63) == 0) r[t >> 6] = s;
    __syncthreads();
    if (t == 0) out[0] = (float)((r[0] + r[1] + r[2] + r[3]) / ((double)4096 * 4096.0));
}

extern "C" void kernel_launch(void* const* d_in, const int* in_sizes, int n_in,
                              void* d_out, int out_size, void* d_ws, size_t ws_size,
                              hipStream_t stream) {
    const float* src = (const float*)d_in[0];
    const float* tgt = (const float*)d_in[1];
    char* ws = (char*)d_ws;
    float* sq    = (float*)ws;
    float* v     = (float*)(ws + 32768);
    float* Fpart = (float*)(ws + FP_OFF);
    unsigned char* img = (unsigned char*)(ws + IMG_OFF);
    float* out = (float*)d_out;

    hipMemsetAsync(ws, 0, 34816, stream);   // sq + v (atomic targets)
    hipLaunchKernelGGL(k_pre, dim3(512), dim3(256), 0, stream, src, tgt, img, sq, v);
    hipLaunchKernelGGL(kmain, dim3(NBLK), dim3(256), 0, stream, img, sq, v, Fpart);
    hipLaunchKernelGGL(k4_out, dim3(1), dim3(256), 0, stream, Fpart, out);
}